// Round 5
// baseline (179.249 us; speedup 1.0000x reference)
//
#include <hip/hip_runtime.h>

// Masked Pearson correlation per row, summed over batch.
// pre, label: [B=32, L=128, N=8192] fp32.  out: [L=128] fp32.
//
// R1: 46.6 us baseline (two kernels); row kernel ~43.6 us = 6.16 TB/s
//     ~= 98% of m13 copy ceiling (6.29 TB/s). Memory-bound.
// R3: nt-hint L3 partitioning -> FETCH_SIZE & dur unchanged; reverted.
// R4: fused last-block-done, FAILED: winner test (old&4095)==4095 picks the
//     LAST block only when counter starts at 0 mod 4096; poison 0xAAAAAAAA
//     made block #1366 win and sum unwritten rows.
// R5: hipMemsetAsync(counter, 0) each launch (memset node is capturable),
//     winner = old == NROWS-1 exactly.

#define THRESH 0.001f

constexpr int B = 32;
constexpr int L = 128;
constexpr int N = 8192;
constexpr int BLOCK = 256;           // multiple of 64 (wave size)
constexpr int ITERS = N / 4 / BLOCK; // 8 float4 loads per input per thread
constexpr int NROWS = B * L;         // 4096

typedef float vfloat4 __attribute__((ext_vector_type(4)));

__device__ inline void accumulate_row(const float* __restrict__ pre_row,
                                      const float* __restrict__ label_row,
                                      float& cnt, float& sp, float& sl,
                                      float& spp, float& sll, float& spl) {
    const vfloat4* p4 = reinterpret_cast<const vfloat4*>(pre_row);
    const vfloat4* l4 = reinterpret_cast<const vfloat4*>(label_row);
    #pragma unroll
    for (int i = 0; i < ITERS; ++i) {
        const int idx = threadIdx.x + i * BLOCK;  // coalesced
        const vfloat4 p = p4[idx];
        const vfloat4 l = l4[idx];
        #pragma unroll
        for (int j = 0; j < 4; ++j) {
            const float pj = p[j];
            const float lj = l[j];
            const float m = ((fabsf(pj) > THRESH) || (fabsf(lj) > THRESH)) ? 1.f : 0.f;
            const float pm = pj * m;
            const float lm = lj * m;
            cnt += m;
            sp  += pm;
            sl  += lm;
            spp += pm * pj;
            sll += lm * lj;
            spl += pm * lj;
        }
    }
}

__device__ inline float reduce_cc(float cnt, float sp, float sl,
                                  float spp, float sll, float spl) {
    // Wave reduce (64 lanes), then LDS across 4 waves; returns cc on thread 0.
    #pragma unroll
    for (int off = 32; off > 0; off >>= 1) {
        cnt += __shfl_down(cnt, off);
        sp  += __shfl_down(sp,  off);
        sl  += __shfl_down(sl,  off);
        spp += __shfl_down(spp, off);
        sll += __shfl_down(sll, off);
        spl += __shfl_down(spl, off);
    }
    __shared__ float red[BLOCK / 64][6];
    const int lane = threadIdx.x & 63;
    const int wave = threadIdx.x >> 6;
    if (lane == 0) {
        red[wave][0] = cnt; red[wave][1] = sp;  red[wave][2] = sl;
        red[wave][3] = spp; red[wave][4] = sll; red[wave][5] = spl;
    }
    __syncthreads();
    float cc = 0.f;
    if (threadIdx.x == 0) {
        float c = 0.f, a = 0.f, b = 0.f, qp = 0.f, ql = 0.f, q = 0.f;
        #pragma unroll
        for (int w = 0; w < BLOCK / 64; ++w) {
            c  += red[w][0]; a  += red[w][1]; b  += red[w][2];
            qp += red[w][3]; ql += red[w][4]; q  += red[w][5];
        }
        const float cov = q  - a * b / c;
        const float vp  = qp - a * a / c;
        const float vl  = ql - b * b / c;
        cc = cov / sqrtf(vp * vl);
    }
    return cc;
}

// Fused: per-row cc + last-block batch sum.  row_cc layout [l][b].
__global__ __launch_bounds__(BLOCK) void cc_fused_kernel(const float* __restrict__ pre,
                                                         const float* __restrict__ label,
                                                         float* __restrict__ row_cc,
                                                         unsigned int* __restrict__ counter,
                                                         float* __restrict__ out) {
    const int row = blockIdx.x;  // row = b*L + l
    const float* prow = pre   + (size_t)row * N;
    const float* lrow = label + (size_t)row * N;

    float cnt = 0.f, sp = 0.f, sl = 0.f, spp = 0.f, sll = 0.f, spl = 0.f;
    accumulate_row(prow, lrow, cnt, sp, sl, spp, sll, spl);
    const float cc = reduce_cc(cnt, sp, sl, spp, sll, spl);

    __shared__ unsigned int s_winner;
    if (threadIdx.x == 0) {
        const int bi = row >> 7;       // row / L
        const int li = row & (L - 1);  // row % L
        // Agent-scope store: visible across XCDs for the winner's reads.
        __hip_atomic_store(&row_cc[li * B + bi], cc,
                           __ATOMIC_RELAXED, __HIP_MEMORY_SCOPE_AGENT);
        __threadfence();  // release: row_cc store ordered before counter add
        const unsigned int old = atomicAdd(counter, 1u);
        // counter is memset to 0 on the stream before this kernel, so the
        // block seeing old == NROWS-1 is exactly the LAST to finish.
        s_winner = (old == NROWS - 1u) ? 1u : 0u;
    }
    __syncthreads();

    if (s_winner) {
        __threadfence();  // acquire side
        if (threadIdx.x < L) {
            const int l = threadIdx.x;
            float s = 0.f;
            #pragma unroll
            for (int b = 0; b < B; ++b) {
                s += __hip_atomic_load(&row_cc[l * B + b],
                                       __ATOMIC_RELAXED, __HIP_MEMORY_SCOPE_AGENT);
            }
            out[l] = s;
        }
    }
}

// ---- Fallback (two-kernel) path, used only if ws_size is too small ----
__global__ __launch_bounds__(BLOCK) void cc_row_kernel(const float* __restrict__ pre,
                                                       const float* __restrict__ label,
                                                       float* __restrict__ row_cc) {
    const int row = blockIdx.x;
    const float* prow = pre   + (size_t)row * N;
    const float* lrow = label + (size_t)row * N;
    float cnt = 0.f, sp = 0.f, sl = 0.f, spp = 0.f, sll = 0.f, spl = 0.f;
    accumulate_row(prow, lrow, cnt, sp, sl, spp, sll, spl);
    const float cc = reduce_cc(cnt, sp, sl, spp, sll, spl);
    if (threadIdx.x == 0) {
        const int bi = row >> 7;
        const int li = row & (L - 1);
        row_cc[li * B + bi] = cc;
    }
}

__global__ __launch_bounds__(L) void cc_sum_kernel(const float* __restrict__ row_cc,
                                                   float* __restrict__ out) {
    const int l = threadIdx.x;
    float s = 0.f;
    #pragma unroll
    for (int b = 0; b < B; ++b) s += row_cc[l * B + b];
    out[l] = s;
}

extern "C" void kernel_launch(void* const* d_in, const int* in_sizes, int n_in,
                              void* d_out, int out_size, void* d_ws, size_t ws_size,
                              hipStream_t stream) {
    const float* pre   = (const float*)d_in[0];
    const float* label = (const float*)d_in[1];
    float* out = (float*)d_out;

    if (ws_size >= 512 + NROWS * sizeof(float)) {
        unsigned int* counter = (unsigned int*)d_ws;               // 4 B @ offset 0
        float* row_cc = (float*)((char*)d_ws + 512);               // 16 KiB @ offset 512
        hipMemsetAsync(counter, 0, sizeof(unsigned int), stream);  // capturable memset node
        cc_fused_kernel<<<NROWS, BLOCK, 0, stream>>>(pre, label, row_cc, counter, out);
    } else {
        float* row_cc = (float*)d_ws;
        cc_row_kernel<<<NROWS, BLOCK, 0, stream>>>(pre, label, row_cc);
        cc_sum_kernel<<<1, L, 0, stream>>>(row_cc, out);
    }
}

// Round 6
// 49.819 us; speedup vs baseline: 3.5980x; 3.5980x over previous
//
#include <hip/hip_runtime.h>

// Masked Pearson correlation per row, summed over batch.
// pre, label: [B=32, L=128, N=8192] fp32.  out: [L=128] fp32.
//
// R1: 46.6 us baseline (two kernels); row kernel ~43.6 us = 6.16 TB/s
//     ~= 98% of m13 copy ceiling (6.29 TB/s). Memory-bound.
// R3: nt-hint L3 partitioning -> FETCH_SIZE & dur unchanged; reverted.
// R5: fused last-block-done: PASSED but 300 us — per-block __threadfence()
//     lowers to buffer_wbl2 (L2 writeback walk) x4096 blocks -> memory system
//     serialized. NEVER put a device-scope fence in every block.
// R6: drop the fence/counter entirely: each block atomicAdd's its cc into
//     out[l] (device-scope RMW at the coherent point, no cross-block reads).
//     d_out zeroed by a capturable hipMemsetAsync node each launch.

#define THRESH 0.001f

constexpr int B = 32;
constexpr int L = 128;
constexpr int N = 8192;
constexpr int BLOCK = 256;           // multiple of 64 (wave size)
constexpr int ITERS = N / 4 / BLOCK; // 8 float4 loads per input per thread
constexpr int NROWS = B * L;         // 4096

typedef float vfloat4 __attribute__((ext_vector_type(4)));

__device__ inline void accumulate_row(const float* __restrict__ pre_row,
                                      const float* __restrict__ label_row,
                                      float& cnt, float& sp, float& sl,
                                      float& spp, float& sll, float& spl) {
    const vfloat4* p4 = reinterpret_cast<const vfloat4*>(pre_row);
    const vfloat4* l4 = reinterpret_cast<const vfloat4*>(label_row);
    #pragma unroll
    for (int i = 0; i < ITERS; ++i) {
        const int idx = threadIdx.x + i * BLOCK;  // coalesced
        const vfloat4 p = p4[idx];
        const vfloat4 l = l4[idx];
        #pragma unroll
        for (int j = 0; j < 4; ++j) {
            const float pj = p[j];
            const float lj = l[j];
            const float m = ((fabsf(pj) > THRESH) || (fabsf(lj) > THRESH)) ? 1.f : 0.f;
            const float pm = pj * m;
            const float lm = lj * m;
            cnt += m;
            sp  += pm;
            sl  += lm;
            spp += pm * pj;
            sll += lm * lj;
            spl += pm * lj;
        }
    }
}

__device__ inline float reduce_cc(float cnt, float sp, float sl,
                                  float spp, float sll, float spl) {
    // Wave reduce (64 lanes), then LDS across 4 waves; returns cc on thread 0.
    #pragma unroll
    for (int off = 32; off > 0; off >>= 1) {
        cnt += __shfl_down(cnt, off);
        sp  += __shfl_down(sp,  off);
        sl  += __shfl_down(sl,  off);
        spp += __shfl_down(spp, off);
        sll += __shfl_down(sll, off);
        spl += __shfl_down(spl, off);
    }
    __shared__ float red[BLOCK / 64][6];
    const int lane = threadIdx.x & 63;
    const int wave = threadIdx.x >> 6;
    if (lane == 0) {
        red[wave][0] = cnt; red[wave][1] = sp;  red[wave][2] = sl;
        red[wave][3] = spp; red[wave][4] = sll; red[wave][5] = spl;
    }
    __syncthreads();
    float cc = 0.f;
    if (threadIdx.x == 0) {
        float c = 0.f, a = 0.f, b = 0.f, qp = 0.f, ql = 0.f, q = 0.f;
        #pragma unroll
        for (int w = 0; w < BLOCK / 64; ++w) {
            c  += red[w][0]; a  += red[w][1]; b  += red[w][2];
            qp += red[w][3]; ql += red[w][4]; q  += red[w][5];
        }
        const float cov = q  - a * b / c;
        const float vp  = qp - a * a / c;
        const float vl  = ql - b * b / c;
        cc = cov / sqrtf(vp * vl);
    }
    return cc;
}

// One block per row; thread 0 adds this row's cc into out[l].
__global__ __launch_bounds__(BLOCK) void cc_fused_kernel(const float* __restrict__ pre,
                                                         const float* __restrict__ label,
                                                         float* __restrict__ out) {
    const int row = blockIdx.x;  // row = b*L + l
    const float* prow = pre   + (size_t)row * N;
    const float* lrow = label + (size_t)row * N;

    float cnt = 0.f, sp = 0.f, sl = 0.f, spp = 0.f, sll = 0.f, spl = 0.f;
    accumulate_row(prow, lrow, cnt, sp, sl, spp, sll, spl);
    const float cc = reduce_cc(cnt, sp, sl, spp, sll, spl);

    if (threadIdx.x == 0) {
        const int li = row & (L - 1);  // row % L
        // Device-scope RMW at the coherent point; no fence, no cross-block
        // reads. 32 adds per address over ~44 us -> negligible contention.
        atomicAdd(&out[li], cc);
    }
}

extern "C" void kernel_launch(void* const* d_in, const int* in_sizes, int n_in,
                              void* d_out, int out_size, void* d_ws, size_t ws_size,
                              hipStream_t stream) {
    const float* pre   = (const float*)d_in[0];
    const float* label = (const float*)d_in[1];
    float* out = (float*)d_out;

    // Zero the 512 B output each launch (memset nodes are graph-capturable);
    // required because the kernel accumulates into out via atomicAdd.
    hipMemsetAsync(out, 0, L * sizeof(float), stream);
    cc_fused_kernel<<<NROWS, BLOCK, 0, stream>>>(pre, label, out);
}

// Round 7
// 46.840 us; speedup vs baseline: 3.8268x; 1.0636x over previous
//
#include <hip/hip_runtime.h>

// Masked Pearson correlation per row, summed over batch.
// pre, label: [B=32, L=128, N=8192] fp32.  out: [L=128] fp32.
//
// FINAL (= R1 structure, proven 46.58 us). Single-pass six-sum rewrite of the
// masked Pearson cc; one 256-thread block per row; float4 coalesced loads;
// wave shuffle + LDS reduce; tiny dependent sum kernel over batch.
//
// Journal:
//  R1: 46.6 us. Row kernel ~43.6 us = 6.16 TB/s ~= 98% of m13 copy ceiling
//      (6.29 TB/s). FETCH_SIZE 131 MB of 268 MB read (L3 serves ~half, but at
//      no speed advantage -> fabric-limited, not DRAM-limited).
//  R3: __builtin_nontemporal_load L3 partitioning: FETCH_SIZE & dur unchanged
//      -> no L3-steering mechanism at HIP level on gfx950. Reverted.
//  R5: last-block-done fusion with per-block __threadfence(): 300 us.
//      Agent/device release fence lowers to an L2 writeback walk (buffer_wbl2)
//      x4096 blocks -> memory system serialized. Never per-block fences.
//  R6: fence-free fusion via atomicAdd(&out[l], cc) + memset node: 49.8 us
//      (+3.2). Serial memset->kernel dependency + end-of-kernel atomic burst
//      cost more than the saved launch. Fusion avenue closed.
//  R7: revert to R1. Remaining gap to the ~45 us structural floor is ~3%.

#define THRESH 0.001f

constexpr int B = 32;
constexpr int L = 128;
constexpr int N = 8192;
constexpr int BLOCK = 256;           // multiple of 64 (wave size)
constexpr int ITERS = N / 4 / BLOCK; // 8 float4 loads per input per thread

__global__ __launch_bounds__(BLOCK) void cc_row_kernel(const float* __restrict__ pre,
                                                       const float* __restrict__ label,
                                                       float* __restrict__ row_cc) {
    const int row = blockIdx.x;  // row = b*L + l, 0..4095
    const float4* p4 = reinterpret_cast<const float4*>(pre)   + (size_t)row * (N / 4);
    const float4* l4 = reinterpret_cast<const float4*>(label) + (size_t)row * (N / 4);

    float cnt = 0.f, sp = 0.f, sl = 0.f, spp = 0.f, sll = 0.f, spl = 0.f;

    #pragma unroll
    for (int i = 0; i < ITERS; ++i) {
        const int idx = threadIdx.x + i * BLOCK;   // coalesced: lane i -> consecutive float4
        const float4 p = p4[idx];
        const float4 l = l4[idx];
        const float pv[4] = {p.x, p.y, p.z, p.w};
        const float lv[4] = {l.x, l.y, l.z, l.w};
        #pragma unroll
        for (int j = 0; j < 4; ++j) {
            const float pj = pv[j];
            const float lj = lv[j];
            const float m = ((fabsf(pj) > THRESH) || (fabsf(lj) > THRESH)) ? 1.f : 0.f;
            const float pm = pj * m;
            const float lm = lj * m;
            cnt += m;
            sp  += pm;
            sl  += lm;
            spp += pm * pj;
            sll += lm * lj;
            spl += pm * lj;
        }
    }

    // Reduce 6 values across the 64-lane wave.
    #pragma unroll
    for (int off = 32; off > 0; off >>= 1) {
        cnt += __shfl_down(cnt, off);
        sp  += __shfl_down(sp,  off);
        sl  += __shfl_down(sl,  off);
        spp += __shfl_down(spp, off);
        sll += __shfl_down(sll, off);
        spl += __shfl_down(spl, off);
    }

    // Reduce across the 4 waves via LDS.
    __shared__ float red[BLOCK / 64][6];
    const int lane = threadIdx.x & 63;
    const int wave = threadIdx.x >> 6;
    if (lane == 0) {
        red[wave][0] = cnt; red[wave][1] = sp;  red[wave][2] = sl;
        red[wave][3] = spp; red[wave][4] = sll; red[wave][5] = spl;
    }
    __syncthreads();

    if (threadIdx.x == 0) {
        float c = 0.f, a = 0.f, b = 0.f, qp = 0.f, ql = 0.f, q = 0.f;
        #pragma unroll
        for (int w = 0; w < BLOCK / 64; ++w) {
            c  += red[w][0]; a  += red[w][1]; b  += red[w][2];
            qp += red[w][3]; ql += red[w][4]; q  += red[w][5];
        }
        // cov   = sum(pl*m) - sum(p*m)*sum(l*m)/cnt
        // var_p = sum(p^2*m) - sum(p*m)^2/cnt   (same for l)
        const float cov = q  - a * b / c;
        const float vp  = qp - a * a / c;
        const float vl  = ql - b * b / c;
        row_cc[row] = cov / sqrtf(vp * vl);
    }
}

// Sum cc over batch: out[l] = sum_b row_cc[b*L + l].  Deterministic (no atomics).
__global__ __launch_bounds__(L) void cc_sum_kernel(const float* __restrict__ row_cc,
                                                   float* __restrict__ out) {
    const int l = threadIdx.x;
    float s = 0.f;
    #pragma unroll
    for (int b = 0; b < B; ++b) s += row_cc[b * L + l];
    out[l] = s;
}

extern "C" void kernel_launch(void* const* d_in, const int* in_sizes, int n_in,
                              void* d_out, int out_size, void* d_ws, size_t ws_size,
                              hipStream_t stream) {
    const float* pre   = (const float*)d_in[0];
    const float* label = (const float*)d_in[1];
    float* out    = (float*)d_out;
    float* row_cc = (float*)d_ws;   // 4096 floats = 16 KiB scratch

    cc_row_kernel<<<B * L, BLOCK, 0, stream>>>(pre, label, row_cc);
    cc_sum_kernel<<<1, L, 0, stream>>>(row_cc, out);
}